// Round 7
// baseline (296.220 us; speedup 1.0000x reference)
//
#include <hip/hip_runtime.h>

typedef unsigned short u16;
typedef unsigned char u8;
typedef unsigned int u32;
typedef short s16x8 __attribute__((ext_vector_type(8)));
typedef float f32x4 __attribute__((ext_vector_type(4)));

#define AS1 __attribute__((address_space(1)))
#define AS3 __attribute__((address_space(3)))

// B=2, SQ=SKV=2048, H=1024, NH=16, HD=64
#define LOG2E 1.4426950408889634f

__device__ __forceinline__ u16 f2bf(float f) {
  unsigned u = __float_as_uint(f);
  u += 0x7fffu + ((u >> 16) & 1u);      // RNE
  return (u16)(u >> 16);
}
__device__ __forceinline__ float bf2f(u16 b) {
  return __uint_as_float(((unsigned)b) << 16);
}
__device__ __forceinline__ u32 cvtpk(float lo, float hi) {  // bf16(lo) | bf16(hi)<<16, RNE
  u32 r;
  asm("v_cvt_pk_bf16_f32 %0, %1, %2" : "=v"(r) : "v"(lo), "v"(hi));
  return r;
}
__device__ __forceinline__ void gld16(const void* g, void* l) {
  __builtin_amdgcn_global_load_lds((const AS1 unsigned int*)g,
                                   (AS3 unsigned int*)l, 16, 0, 0);
}

// ---------------- prep: fp32 -> bf16 (+ additive mask, pre-scaled by log2e) ----------------
__global__ __launch_bounds__(256) void prep_kernel(
    const float* __restrict__ qs, const float* __restrict__ kvs, const float* __restrict__ mk,
    const float* __restrict__ wq, const float* __restrict__ wk, const float* __restrict__ wv,
    const float* __restrict__ wo,
    u16* __restrict__ q_bf, u16* __restrict__ kv_bf, u16* __restrict__ am_bf,
    u16* __restrict__ wq_bf, u16* __restrict__ wk_bf, u16* __restrict__ wv_bf,
    u16* __restrict__ wo_bf)
{
  const int stride = gridDim.x * blockDim.x;
  const float mscale = -10000.f * LOG2E;
  for (int v = blockIdx.x * blockDim.x + threadIdx.x; v < 5242880; v += stride) {
    const float* s; u16* d; int off; bool ismask = false;
    if (v < 1048576)      { s = qs;  d = q_bf;  off = v; }
    else if (v < 2097152) { s = kvs; d = kv_bf; off = v - 1048576; }
    else if (v < 2359296) { s = wq;  d = wq_bf; off = v - 2097152; }
    else if (v < 2621440) { s = wk;  d = wk_bf; off = v - 2359296; }
    else if (v < 2883584) { s = wv;  d = wv_bf; off = v - 2621440; }
    else if (v < 3145728) { s = wo;  d = wo_bf; off = v - 2883584; }
    else                  { s = mk;  d = am_bf; off = v - 3145728; ismask = true; }
    float4 f = ((const float4*)s)[off];
    if (ismask) {
      f.x = (1.f - f.x) * mscale; f.y = (1.f - f.y) * mscale;
      f.z = (1.f - f.z) * mscale; f.w = (1.f - f.w) * mscale;
    }
    uint2 o;
    o.x = cvtpk(f.x, f.y);
    o.y = cvtpk(f.z, f.w);
    ((uint2*)d)[off] = o;
  }
}

// ------------- mask tile flags: byte fid = 1 if 64q x 64kv tile is all (-)0 -------------
__global__ __launch_bounds__(256) void flag_kernel(const u16* __restrict__ am,
                                                   u8* __restrict__ flags)
{
  const int fid = blockIdx.x;           // [0,2048) = b*1024 + qt*32 + kt
  const int kt = fid & 31, qt = (fid >> 5) & 31, b = fid >> 10;
  const int t = threadIdx.x;
  const int row = t >> 2, seg = t & 3;
  const u16* p = am + ((size_t)(b * 2048 + qt * 64 + row)) * 2048 + kt * 64 + seg * 16;
  const uint4 v0 = *(const uint4*)p;
  const uint4 v1 = *(const uint4*)(p + 8);
  const u32 acc = v0.x | v0.y | v0.z | v0.w | v1.x | v1.y | v1.z | v1.w;
  const bool z = (acc & 0x7fff7fffu) == 0;   // bf16 +/-0 in both halves
  const bool wz = __all(z);
  __shared__ int ok[4];
  if ((t & 63) == 0) ok[t >> 6] = wz;
  __syncthreads();
  if (t == 0) flags[fid] = (ok[0] & ok[1] & ok[2] & ok[3]) ? 1 : 0;
}

// ---------- 128x128 bf16 NT GEMM, 8 waves (512 thr), ring-3 counted vmcnt ----------
// wave w -> 32x64 sub-tile: 8 MFMA + 6 ds_read_b128/step; 2 gld16/wave/step.
template<int EPI>   // 0: bf16 head-split out; 2: bf16 V^T out
__device__ __forceinline__ void gemm_body(
    const u16* __restrict__ A, const u16* __restrict__ W, const float* __restrict__ bias,
    void* __restrict__ outp, float alpha, int m0, int n0)
{
  __shared__ u16 As[3][4096], Bs[3][4096];
  const int tid = threadIdx.x, wave = tid >> 6, lane = tid & 63;
  const int l15 = lane & 15, l4 = lane >> 4;
  const int wr = wave >> 1, wc = wave & 1;

  const int srow = wave * 16 + (lane >> 2);
  const int soct = ((lane & 3) ^ ((lane >> 3) & 3)) * 8;
  const u16* aS = A + (size_t)(m0 + srow) * 1024 + soct;
  const u16* bS = W + (size_t)(n0 + srow) * 1024 + soct;
  const int dOff = wave * 512;

  const int fswz = (l15 >> 1) & 3;
  const int afBase = (wr * 32 + l15) * 32 + ((l4 ^ fswz) * 8);
  const int bfBase = (wc * 64 + l15) * 32 + ((l4 ^ fswz) * 8);

  f32x4 acc[2][4] = {};

  auto stage = [&](int buf, int kt) {
    const int ko = kt * 32;
    gld16(aS + ko, &As[buf][dOff]);
    gld16(bS + ko, &Bs[buf][dOff]);
  };

  stage(0, 0);
  stage(1, 1);

  int cb = 0;
  for (int kt = 0; kt < 32; ++kt) {
    if (kt < 31) asm volatile("s_waitcnt vmcnt(2)" ::: "memory");
    else         asm volatile("s_waitcnt vmcnt(0)" ::: "memory");
    __builtin_amdgcn_s_barrier();
    asm volatile("" ::: "memory");
    if (kt < 30) {
      int sb = cb + 2; if (sb >= 3) sb -= 3;
      stage(sb, kt + 2);
    }
    s16x8 af[2], bf[4];
    #pragma unroll
    for (int m = 0; m < 2; ++m) af[m] = *(const s16x8*)&As[cb][afBase + m * 512];
    #pragma unroll
    for (int n = 0; n < 4; ++n) bf[n] = *(const s16x8*)&Bs[cb][bfBase + n * 512];
    #pragma unroll
    for (int m = 0; m < 2; ++m)
      #pragma unroll
      for (int n = 0; n < 4; ++n)
        acc[m][n] = __builtin_amdgcn_mfma_f32_16x16x32_bf16(af[m], bf[n], acc[m][n], 0, 0, 0);
    asm volatile("" ::: "memory");
    cb = (cb + 1 == 3) ? 0 : cb + 1;
  }

  #pragma unroll
  for (int n = 0; n < 4; ++n) {
    const int col = n0 + wc * 64 + n * 16 + l15;
    #pragma unroll
    for (int m = 0; m < 2; ++m) {
      #pragma unroll
      for (int r = 0; r < 4; ++r) {
        const int row = m0 + wr * 32 + m * 16 + l4 * 4 + r;
        if constexpr (EPI == 0) {
          const float val = (acc[m][n][r] + (bias ? bias[col] : 0.f)) * alpha;
          const int bb = row >> 11, ss = row & 2047, hh = col >> 6, dd = col & 63;
          ((u16*)outp)[(((size_t)(bb * 16 + hh)) * 2048 + ss) * 64 + dd] = f2bf(val);
        } else {  // EPI==2: V^T out [B*NH][64][2048]
          const float val = acc[m][n][r] + bias[row];
          const int hh = row >> 6, dd = row & 63, bb = col >> 11, ss = col & 2047;
          ((u16*)outp)[(((size_t)(bb * 16 + hh)) * 64 + dd) * 2048 + ss] = f2bf(val);
        }
      }
    }
  }
}

__global__ __launch_bounds__(512) void gemm_qkv(
    const u16* __restrict__ qbf, const u16* __restrict__ kvbf,
    const u16* __restrict__ wqb, const u16* __restrict__ wkb, const u16* __restrict__ wvb,
    const float* __restrict__ bq, const float* __restrict__ bv,
    u16* __restrict__ Qh, u16* __restrict__ Kh, u16* __restrict__ Vt)
{
  const int bid = blockIdx.x;
  const int swz = (bid & 7) * 32 + (bid >> 3);   // XCD-contiguous chunks
  const int which = blockIdx.y;
  if (which == 0)   // fold (1/sqrt(64)) * log2(e) into Q so attn can use exp2
    gemm_body<0>(qbf, wqb, bq, Qh, 0.125f * LOG2E, (swz >> 3) * 128, (swz & 7) * 128);
  else if (which == 1)
    gemm_body<0>(kvbf, wkb, nullptr, Kh, 1.0f, (swz >> 3) * 128, (swz & 7) * 128);
  else   // V^T = Wv * KV^T  (M=1024 d-rows, N=4096 s-cols)
    gemm_body<2>(wvb, kvbf, bv, Vt, 1.0f, (bid >> 5) * 128,
                 ((bid & 7) + ((bid >> 3) & 3) * 8) * 128);
}

// ---------- output GEMM: 64x64 tiles, 1024 blocks (4/CU), 4 waves, ring-4 ----------
__global__ __launch_bounds__(256) void gemm_fin(
    const u16* __restrict__ ctx, const u16* __restrict__ wob,
    const float* __restrict__ bo, float* __restrict__ out)
{
  __shared__ u16 As[4][2048], Bs[4][2048];
  const int tid = threadIdx.x, wave = tid >> 6, lane = tid & 63;
  const int l15 = lane & 15, l4 = lane >> 4;
  const int wr = wave >> 1, wc = wave & 1;
  const int bid = blockIdx.x;
  const int swz = (bid & 7) * 128 + (bid >> 3);  // XCD-chunked (1024 = 8*128)
  const int m0 = (swz >> 4) * 64, n0 = (swz & 15) * 64;

  const int srow = wave * 16 + (lane >> 2);
  const int soct = ((lane & 3) ^ ((lane >> 3) & 3)) * 8;
  const u16* aS = ctx + (size_t)(m0 + srow) * 1024 + soct;
  const u16* bS = wob + (size_t)(n0 + srow) * 1024 + soct;
  const int dOff = wave * 512;

  const int fswz = (l15 >> 1) & 3;
  const int afBase = (wr * 32 + l15) * 32 + ((l4 ^ fswz) * 8);
  const int bfBase = (wc * 32 + l15) * 32 + ((l4 ^ fswz) * 8);

  f32x4 acc[2][2] = {};

  auto stage = [&](int buf, int kt) {
    const int ko = kt * 32;
    gld16(aS + ko, &As[buf][dOff]);
    gld16(bS + ko, &Bs[buf][dOff]);
  };

  stage(0, 0);
  stage(1, 1);
  stage(2, 2);

  int cb = 0;
  for (int kt = 0; kt < 32; ++kt) {
    if (kt < 30)      asm volatile("s_waitcnt vmcnt(4)" ::: "memory");
    else if (kt == 30) asm volatile("s_waitcnt vmcnt(2)" ::: "memory");
    else               asm volatile("s_waitcnt vmcnt(0)" ::: "memory");
    __builtin_amdgcn_s_barrier();
    asm volatile("" ::: "memory");
    if (kt < 29) stage((cb + 3) & 3, kt + 3);
    s16x8 af[2], bf[2];
    #pragma unroll
    for (int m = 0; m < 2; ++m) af[m] = *(const s16x8*)&As[cb][afBase + m * 512];
    #pragma unroll
    for (int n = 0; n < 2; ++n) bf[n] = *(const s16x8*)&Bs[cb][bfBase + n * 512];
    #pragma unroll
    for (int m = 0; m < 2; ++m)
      #pragma unroll
      for (int n = 0; n < 2; ++n)
        acc[m][n] = __builtin_amdgcn_mfma_f32_16x16x32_bf16(af[m], bf[n], acc[m][n], 0, 0, 0);
    asm volatile("" ::: "memory");
    cb = (cb + 1) & 3;
  }

  #pragma unroll
  for (int n = 0; n < 2; ++n) {
    const int col = n0 + wc * 32 + n * 16 + l15;
    const float bv = bo[col];
    #pragma unroll
    for (int m = 0; m < 2; ++m) {
      #pragma unroll
      for (int r = 0; r < 4; ++r) {
        const int row = m0 + wr * 32 + m * 16 + l4 * 4 + r;
        out[(size_t)row * 1024 + col] = acc[m][n][r] + bv;
      }
    }
  }
}

// ---------------- flash attention: 64 q/block, 4 waves x 16 q, 4 blocks/CU ----------------
// grid 1024 XCD-chunked (4 heads/XCD). S^T = K*Q^T (kv lane-local). dbuf-2 raw
// barriers; per-tile flag byte skips mask work; l-sum via MFMA ones-B trick.
__global__ __launch_bounds__(256) void attn_kernel(
    const u16* __restrict__ Qh, const u16* __restrict__ Kh,
    const u16* __restrict__ Vt, const u16* __restrict__ am,
    const u8* __restrict__ flags, u16* __restrict__ ctx)
{
  __shared__ u16 Ks[2][4096];        // [64 kv][64 d] swizzled
  __shared__ u16 Vs[2][4096];        // [64 d][64 kv] swizzled
  __shared__ u16 Pl[4][1024];        // per wave: [16 q][64 kv] swizzled
  const int tid = threadIdx.x, wave = tid >> 6, lane = tid & 63;
  const int l15 = lane & 15, l4 = lane >> 4;
  const int x7 = l15 & 7;
  const int bid = blockIdx.x;
  const int pos = (bid & 7) * 128 + (bid >> 3); // XCD-chunked (1024 = 8*128)
  const int hh = pos >> 5, qt = pos & 31;
  const int b = hh >> 4, h = hh & 15;
  const int q0 = qt * 64;
  const u16* Qb = Qh + (size_t)hh * 2048 * 64;
  const u16* Kb = Kh + (size_t)hh * 2048 * 64;
  const u16* Vb = Vt + (size_t)hh * 64 * 2048;

  // tile-skip bitmask from flag bytes (uniform per block)
  u32 fbits = 0;
  {
    const u8* fb = flags + (b * 32 + qt) * 32;
    #pragma unroll
    for (int i = 0; i < 32; ++i) fbits |= (fb[i] ? 1u : 0u) << i;
  }

  // Q B-frag (col=q=l15, k=d=l4*8+j); 1/8*log2e folded at projection
  const int qrow = q0 + wave * 16 + l15;
  const s16x8 qf0 = *(const s16x8*)(Qb + (size_t)qrow * 64 + l4 * 8);
  const s16x8 qf1 = *(const s16x8*)(Qb + (size_t)qrow * 64 + 32 + l4 * 8);
  const u16* amrow = am + ((size_t)b * 2048 + qrow) * 2048;

  const s16x8 ones = {16256, 16256, 16256, 16256, 16256, 16256, 16256, 16256}; // bf16 1.0

  // staging: 8-lane clusters cover one 128B row; slot XOR-swizzled via global src
  const int sr = wave * 16 + (lane >> 3);
  const int ss = ((lane & 7) ^ ((lane >> 3) & 7)) * 8;
  const u16* kS0 = Kb + (size_t)sr * 64 + ss;
  const u16* kS1 = Kb + (size_t)(sr + 8) * 64 + ss;
  const u16* vS0 = Vb + (size_t)sr * 2048 + ss;
  const u16* vS1 = Vb + (size_t)(sr + 8) * 2048 + ss;
  const int kd0 = wave * 1024, kd1 = kd0 + 512;

  auto stage = [&](int buf, int kt) {
    const int kv0 = kt * 64;
    gld16(kS0 + (size_t)kv0 * 64, &Ks[buf][kd0]);
    gld16(kS1 + (size_t)kv0 * 64, &Ks[buf][kd1]);
    gld16(vS0 + kv0, &Vs[buf][kd0]);
    gld16(vS1 + kv0, &Vs[buf][kd1]);
  };

  f32x4 of[4] = {};
  f32x4 lr = {};                        // row-sum accumulator (C-layout rows)
  float m_run = -1e30f;

  stage(0, 0);
  asm volatile("s_waitcnt vmcnt(0)" ::: "memory");
  __builtin_amdgcn_s_barrier();
  asm volatile("" ::: "memory");

  int cur = 0;
  for (int kt = 0; kt < 32; ++kt) {
    if (kt < 31) stage(cur ^ 1, kt + 1);
    const int kv0 = kt * 64;
    const bool skip = (fbits >> kt) & 1u;

    ushort4 mk4[4];
    if (!skip) {
      #pragma unroll
      for (int nf = 0; nf < 4; ++nf)
        mk4[nf] = *(const ushort4*)(amrow + kv0 + nf * 16 + l4 * 4);
    }

    // S^T = K * Q^T : lane holds q=l15, kv_local = nf*16 + l4*4 + r
    f32x4 sf[4];
    __builtin_amdgcn_s_setprio(1);
    #pragma unroll
    for (int nf = 0; nf < 4; ++nf) {
      const s16x8 ka0 = *(const s16x8*)&Ks[cur][nf * 1024 + l15 * 64 + ((l4 ^ x7) * 8)];
      const s16x8 ka1 = *(const s16x8*)&Ks[cur][nf * 1024 + l15 * 64 + (((4 + l4) ^ x7) * 8)];
      f32x4 s = {0.f, 0.f, 0.f, 0.f};
      s = __builtin_amdgcn_mfma_f32_16x16x32_bf16(ka0, qf0, s, 0, 0, 0);
      s = __builtin_amdgcn_mfma_f32_16x16x32_bf16(ka1, qf1, s, 0, 0, 0);
      sf[nf] = s;
    }
    __builtin_amdgcn_s_setprio(0);

    // online softmax (log2 domain, defer-max THR = 8 nats)
    float tmax = -1e30f;
    #pragma unroll
    for (int nf = 0; nf < 4; ++nf)
      #pragma unroll
      for (int r = 0; r < 4; ++r) {
        float sv = sf[nf][r];
        if (!skip) sv += bf2f(((const u16*)&mk4[nf])[r]);
        sf[nf][r] = sv;
        tmax = fmaxf(tmax, sv);
      }
    tmax = fmaxf(tmax, __shfl_xor(tmax, 16));
    tmax = fmaxf(tmax, __shfl_xor(tmax, 32));

    const float mOld = m_run;
    float mn = mOld;
    if (!__all(tmax <= mOld + 11.54f)) {        // rescale path (rare after tile 0)
      mn = fmaxf(mOld, tmax);
      const float sc = exp2f(mOld - mn);
      m_run = mn;
      float sq[4];
      #pragma unroll
      for (int r = 0; r < 4; ++r) sq[r] = __shfl(sc, l4 * 4 + r);
      #pragma unroll
      for (int r = 0; r < 4; ++r) lr[r] *= sq[r];
      #pragma unroll
      for (int nd = 0; nd < 4; ++nd)
        #pragma unroll
        for (int r = 0; r < 4; ++r) of[nd][r] *= sq[r];
    }

    u32* pw = (u32*)&Pl[wave][0];
    #pragma unroll
    for (int nf = 0; nf < 4; ++nf) {
      const float p0 = exp2f(sf[nf][0] - mn), p1 = exp2f(sf[nf][1] - mn);
      const float p2 = exp2f(sf[nf][2] - mn), p3 = exp2f(sf[nf][3] - mn);
      u32* w = pw + l15 * 32 + (((nf * 2 + (l4 >> 1)) ^ x7) * 4) + (l4 & 1) * 2;
      w[0] = cvtpk(p0, p1);
      w[1] = cvtpk(p2, p3);
    }

    // O += P * V ; l += P * 1 (ones B-operand -> row-sums land row-indexed)
    __builtin_amdgcn_s_setprio(1);
    #pragma unroll
    for (int kh = 0; kh < 2; ++kh) {
      const s16x8 pa = *(const s16x8*)&Pl[wave][l15 * 64 + (((kh * 4 + l4) ^ x7) * 8)];
      #pragma unroll
      for (int nd = 0; nd < 4; ++nd) {
        const s16x8 vb = *(const s16x8*)&Vs[cur][nd * 1024 + l15 * 64 + (((kh * 4 + l4) ^ x7) * 8)];
        of[nd] = __builtin_amdgcn_mfma_f32_16x16x32_bf16(pa, vb, of[nd], 0, 0, 0);
      }
      lr = __builtin_amdgcn_mfma_f32_16x16x32_bf16(pa, ones, lr, 0, 0, 0);
    }
    __builtin_amdgcn_s_setprio(0);

    if (kt < 31) {
      asm volatile("s_waitcnt vmcnt(0)" ::: "memory");
      __builtin_amdgcn_s_barrier();
      asm volatile("" ::: "memory");
    }
    cur ^= 1;
  }

  // epilogue: normalize + write ctx [B][S][H] bf16 (lr already row-indexed)
  #pragma unroll
  for (int r = 0; r < 4; ++r) {
    const float invq = 1.f / lr[r];
    const int qg = q0 + wave * 16 + l4 * 4 + r;
    const size_t rowbase = ((size_t)b * 2048 + qg) * 1024 + h * 64;
    #pragma unroll
    for (int nd = 0; nd < 4; ++nd)
      ctx[rowbase + nd * 16 + l15] = f2bf(of[nd][r] * invq);
  }
}

// ---------------- launcher ----------------
extern "C" void kernel_launch(void* const* d_in, const int* in_sizes, int n_in,
                              void* d_out, int out_size, void* d_ws, size_t ws_size,
                              hipStream_t stream)
{
  const float* qs = (const float*)d_in[0];
  const float* kvs = (const float*)d_in[1];
  const float* mk = (const float*)d_in[2];
  const float* Wq = (const float*)d_in[3];
  const float* bq = (const float*)d_in[4];
  const float* Wk = (const float*)d_in[5];
  const float* Wv = (const float*)d_in[6];
  const float* bv = (const float*)d_in[7];
  const float* Wo = (const float*)d_in[8];
  const float* bo = (const float*)d_in[9];
  float* out = (float*)d_out;

  char* ws = (char*)d_ws;
  u16* q_bf  = (u16*)(ws + 0);
  u16* kv_bf = (u16*)(ws + 8388608);
  u16* wq_bf = (u16*)(ws + 16777216);
  u16* wk_bf = (u16*)(ws + 18874368);
  u16* wv_bf = (u16*)(ws + 20971520);
  u16* wo_bf = (u16*)(ws + 23068672);
  u16* am_bf = (u16*)(ws + 25165824);
  u16* Qhp   = (u16*)(ws + 41943040);   // [B*NH][2048][64]
  u16* Khp   = (u16*)(ws + 50331648);   // [B*NH][2048][64]
  u16* Vtp   = (u16*)(ws + 58720256);   // [B*NH][64][2048]  (pre-transposed)
  u16* ctxp  = (u16*)(ws + 67108864);   // [B][2048][1024]
  u8* flagsp = (u8*)wq_bf;              // 2 KB; wq_bf is dead after gemm_qkv

  prep_kernel<<<dim3(2048), dim3(256), 0, stream>>>(
      qs, kvs, mk, Wq, Wk, Wv, Wo, q_bf, kv_bf, am_bf, wq_bf, wk_bf, wv_bf, wo_bf);

  gemm_qkv<<<dim3(256, 3), dim3(512), 0, stream>>>(
      q_bf, kv_bf, wq_bf, wk_bf, wv_bf, bq, bv, Qhp, Khp, Vtp);

  flag_kernel<<<dim3(2048), dim3(256), 0, stream>>>(am_bf, flagsp);

  attn_kernel<<<dim3(1024), dim3(256), 0, stream>>>(Qhp, Khp, Vtp, am_bf, flagsp, ctxp);

  gemm_fin<<<dim3(1024), dim3(256), 0, stream>>>(ctxp, wo_bf, bo, out);
}